// Round 8
// baseline (2217.382 us; speedup 1.0000x reference)
//
#include <hip/hip_runtime.h>

// Loihi SNN, 3 layers of (GEMM -> Loihi scan -> delay).
// Round 8: gemm8 restructured for overlap, not lockstep:
//  - 2-deep LDS ring (64 KB total) -> 2 blocks/CU resident; vis grid (400)
//    fits in ONE block-wave (512 slots) -> no tail.
//  - ONE barrier per K-tile (boundary vmcnt(own)+s_barrier). Hazard proof:
//    reads of buf[i&1] are consumed (lgkmcnt before MFMA) before each wave
//    reaches the boundary barrier; all stage-writes go to the other-parity
//    buffer; so pre-MFMA barriers are redundant. Waves slip freely ->
//    ds_read/MFMA overlap within and across blocks.
//  - stages issued FIRST in the body (max in-flight time before the drain).
// Swizzle (key (row>>1)&3) kept exactly as round 7 (conflicts == 0).
//
// W-planes stacked along M (single A stream): W2 = [W_hi; W_mid], M2=2C.
// Scans sum plane pairs (X[c] + X[c+C]) and K-split partials in fixed order.

typedef unsigned short u16;
typedef unsigned int u32;
typedef __attribute__((ext_vector_type(8))) short short8;
typedef __attribute__((ext_vector_type(4))) float f32x4;

#define GLOAD16(g, l)                                                         \
    __builtin_amdgcn_global_load_lds(                                         \
        (const __attribute__((address_space(1))) u32*)(g),                    \
        (__attribute__((address_space(3))) u32*)(l), 16, 0, 0)

__device__ __forceinline__ u16 f2bf_trunc(float x) {
    return (u16)(__float_as_uint(x) >> 16);
}

// ---------------- W -> stacked 2-plane RNE split ----------------
__global__ void split_w2s(const float* __restrict__ W, u16* __restrict__ W2,
                          int C, int K, int KLD)
{
    const int c = blockIdx.y;
    const int k = blockIdx.x * 256 + threadIdx.x;
    if (k >= KLD) return;
    float w = (k < K) ? W[(size_t)c * K + k] : 0.f;
    u32 b  = __float_as_uint(w);
    u32 hb = (b + 0x7FFFu + ((b >> 16) & 1u)) & 0xFFFF0000u;
    float r = w - __uint_as_float(hb);
    u32 rb = __float_as_uint(r);
    u32 mb = (rb + 0x7FFFu + ((rb >> 16) & 1u)) & 0xFFFF0000u;
    W2[(size_t)c * KLD + k]       = (u16)(hb >> 16);
    W2[((size_t)C + c) * KLD + k] = (u16)(mb >> 16);
}

// ------- spikes fp32 [n][I][400] -> bf16 [n*400+t][KLD] (transpose) -------
__global__ __launch_bounds__(256) void cvt_sp(const float* __restrict__ S,
                                              u16* __restrict__ Sp,
                                              int I, int KLD)
{
    __shared__ u16 tile[64][80];
    const int n  = blockIdx.z;
    const int i0 = blockIdx.y * 64;
    const int t0 = blockIdx.x * 64;
    const int tid = threadIdx.x;

    const int il = tid >> 2;
    const int q  = tid & 3;
    const int gi = i0 + il;
    const bool iok = gi < I;
    const float* srow = S + ((size_t)n * I + gi) * 400 + t0;

    #pragma unroll
    for (int s = 0; s < 4; ++s) {
        const int fi = s * 4 + q;
        const int tl = fi * 4;
        float4 v = make_float4(0.f, 0.f, 0.f, 0.f);
        if (iok && (t0 + tl) < 400)
            v = *(const float4*)(srow + tl);
        tile[tl + 0][il] = f2bf_trunc(v.x);
        tile[tl + 1][il] = f2bf_trunc(v.y);
        tile[tl + 2][il] = f2bf_trunc(v.z);
        tile[tl + 3][il] = f2bf_trunc(v.w);
    }
    __syncthreads();

    const int tl = tid >> 2;
    const int iq = tid & 3;
    const int t  = t0 + tl;
    const int go = i0 + iq * 16;
    if (t < 400 && go < KLD) {
        u16* dst = Sp + (size_t)(n * 400 + t) * KLD + go;
        *(short8*)(dst)     = *(const short8*)&tile[tl][iq * 16];
        *(short8*)(dst + 8) = *(const short8*)&tile[tl][iq * 16 + 8];
    }
}

// ---------------- overlap-pipelined bf16 MFMA GEMM ----------------
// X[z][nt][c] = sum_{k in chunk z} A[c][k] * B[nt][k]
// 256(M) x 256(N) tile, BK=32, 8 waves (2M x 4N), wave = 128x64 output.
// LDS: A ring 2x8192 u16 @0 ; B ring 2x8192 u16 @16384  (64 KB total)
__global__ __launch_bounds__(512, 4) void gemm8(
    const u16* __restrict__ A,   // [M2][KLD]
    const u16* __restrict__ B,   // [12800][KLD]
    float* __restrict__ Xbase,   // [z][12800][M2]
    int M2, int KLD, int ktPerZ, int ktTotal)
{
    __shared__ u16 lds[32768];   // 64 KB

    // bijective XCD-aware block swizzle (all launches have nwg % 8 == 0)
    const int Dx = gridDim.x, Dy = gridDim.y;
    int f = blockIdx.x + Dx * (blockIdx.y + Dy * blockIdx.z);
    const int nwg = Dx * Dy * gridDim.z;
    f = (f & 7) * (nwg >> 3) + (f >> 3);
    const int bx = f % Dx;
    const int by = (f / Dx) % Dy;
    const int bz = f / (Dx * Dy);

    const int c0  = bx * 256;
    const int nt0 = by * 256;
    const int kt0 = bz * ktPerZ;
    const int nk  = min(ktTotal - kt0, ktPerZ);
    float* __restrict__ X = Xbase + (size_t)bz * 12800 * M2;

    const int tid  = threadIdx.x;
    const int lane = tid & 63, w = tid >> 6;

    // staging: LDS granule (row=tid>>2, gc=tid&3) <- global granule-col
    // inverse-swizzled with key (row>>1)&3  [both-sides-or-neither, rule 21]
    const int sr  = tid >> 2;                       // 0..127 (half j adds 128)
    const int sgc = (tid & 3) ^ ((sr >> 1) & 3);
    const u16* gA0 = A + (size_t)(c0 + sr) * KLD + (size_t)kt0 * 32 + sgc * 8;
    const u16* gA1 = gA0 + (size_t)128 * KLD;
    const u16* gB0 = B + (size_t)(nt0 + sr) * KLD + (size_t)kt0 * 32 + sgc * 8;
    const u16* gB1 = gB0 + (size_t)128 * KLD;
    u16* const lA0 = &lds[0     + w * 512];
    u16* const lA1 = &lds[4096  + w * 512];
    u16* const lB0 = &lds[16384 + w * 512];
    u16* const lB1 = &lds[16384 + 4096 + w * 512];

#define STAGE_A(i, b) { GLOAD16(gA0 + (size_t)(i) * 32, lA0 + (b) * 8192);    \
                        GLOAD16(gA1 + (size_t)(i) * 32, lA1 + (b) * 8192); }
#define STAGE_B(i, b) { GLOAD16(gB0 + (size_t)(i) * 32, lB0 + (b) * 8192);    \
                        GLOAD16(gB1 + (size_t)(i) * 32, lB1 + (b) * 8192); }
#define FENCE() asm volatile("" ::: "memory")

    // fragment reads: granule col = l16 ^ ((row>>1)&3); row ≡ l15 (mod 16)
    const int wm = w >> 2, wn = w & 3;
    const int l15 = lane & 15, l16 = lane >> 4;
    const int swz  = (l16 ^ ((l15 >> 1) & 3)) * 8;
    const int aOff = (wm * 128 + l15) * 32 + swz;        // + mf*512 + buf*8192
    const int bOff = 16384 + (wn * 64 + l15) * 32 + swz; // + nf*512 + buf*8192

    f32x4 acc[8][4];
    #pragma unroll
    for (int i = 0; i < 8; ++i)
        #pragma unroll
        for (int j = 0; j < 4; ++j)
            acc[i][j] = (f32x4){0.f, 0.f, 0.f, 0.f};

    // prologue: stage tile 0 into buffer 0
    STAGE_A(0, 0); STAGE_B(0, 0);

    for (int i = 0; i < nk; ++i) {
        const int bb = (i & 1) * 8192;

        // K-tile boundary: drain own stage loads, then collective barrier.
        asm volatile("s_waitcnt vmcnt(0)" ::: "memory");
        __builtin_amdgcn_s_barrier();
        FENCE();

        // issue next tile's A stage first (other-parity buffer, max in-flight)
        if (i + 1 < nk) STAGE_A(i + 1, (i + 1) & 1);
        FENCE();

        // phase 1: A m-frags 0..3 + B n-frags 0..3 -> 16 MFMA
        short8 a1[4], bf[4];
        #pragma unroll
        for (int mf = 0; mf < 4; ++mf)
            a1[mf] = *(const short8*)&lds[bb + aOff + mf * 512];
        #pragma unroll
        for (int nf = 0; nf < 4; ++nf)
            bf[nf] = *(const short8*)&lds[bb + bOff + nf * 512];
        __builtin_amdgcn_s_setprio(1);
        #pragma unroll
        for (int mf = 0; mf < 4; ++mf)
            #pragma unroll
            for (int nf = 0; nf < 4; ++nf)
                acc[mf][nf] = __builtin_amdgcn_mfma_f32_16x16x32_bf16(
                    a1[mf], bf[nf], acc[mf][nf], 0, 0, 0);
        __builtin_amdgcn_s_setprio(0);
        FENCE();

        // issue next tile's B stage, then phase 2 (B reused in regs)
        if (i + 1 < nk) STAGE_B(i + 1, (i + 1) & 1);
        FENCE();
        short8 a2[4];
        #pragma unroll
        for (int mf = 0; mf < 4; ++mf)
            a2[mf] = *(const short8*)&lds[bb + aOff + (mf + 4) * 512];
        __builtin_amdgcn_s_setprio(1);
        #pragma unroll
        for (int mf = 0; mf < 4; ++mf)
            #pragma unroll
            for (int nf = 0; nf < 4; ++nf)
                acc[mf + 4][nf] = __builtin_amdgcn_mfma_f32_16x16x32_bf16(
                    a2[mf], bf[nf], acc[mf + 4][nf], 0, 0, 0);
        __builtin_amdgcn_s_setprio(0);
        FENCE();
    }

    // epilogue: D col=lane&15 -> nt, row=(lane>>4)*4+reg -> c (m89-verified)
    #pragma unroll
    for (int mf = 0; mf < 8; ++mf) {
        const int c = c0 + wm * 128 + mf * 16 + l16 * 4;
        #pragma unroll
        for (int nf = 0; nf < 4; ++nf) {
            const int nt = nt0 + wn * 64 + nf * 16 + l15;
            *(f32x4*)&X[(size_t)nt * M2 + c] = acc[mf][nf];
        }
    }
#undef STAGE_A
#undef STAGE_B
#undef FENCE
}

// ---------------- Loihi scans (8-deep pipelined loads, 64-thr blocks) ------
__device__ __forceinline__ float loihi_step(float xt, float& u, float& v)
{
    u = truncf(u * 0.75f) + 64.f * xt;
    v = truncf(v * 0.96875f) + u;
    if (v >= 5120.f) { v = 0.f; return 1.f; }
    return 0.f;
}

// scan_ab: tact (stacked pair) + vis (2 partials, stacked pairs) -> Sc bf16
__global__ __launch_bounds__(64) void scan_ab(const float* __restrict__ Xt,
                                              const float* __restrict__ Xv,
                                              u16* __restrict__ Sc)
{
    const int gid = blockIdx.x * 64 + threadIdx.x;   // 32*1024 threads
    const int n = gid >> 10;
    const int c = gid & 1023;
    const size_t PS = (size_t)12800 * 1024;          // vis partial stride

    u16* srow = Sc + (size_t)(n * 400) * 1024 + c;
    srow[0] = 0;

    float buf[8];
    float u = 0.f, v = 0.f;

    if (c < 512) {
        const float* xr = Xt + (size_t)(n * 400) * 1024 + c;
        #pragma unroll
        for (int d = 0; d < 8; ++d) {
            const size_t o = (size_t)d * 1024;
            buf[d] = xr[o] + xr[o + 512];
        }
        #pragma unroll 8
        for (int t = 0; t < 400; ++t) {
            const float xt = buf[t & 7];
            const int tn = t + 8;
            float nx = 0.f;
            if (tn < 400) {
                const size_t o = (size_t)tn * 1024;
                nx = xr[o] + xr[o + 512];
            }
            buf[t & 7] = nx;
            const float sp = loihi_step(xt, u, v);
            if (t < 399) srow[(size_t)(t + 1) * 1024] = (sp != 0.f) ? (u16)0x3F80 : (u16)0;
        }
    } else {
        const float* xr = Xv + (size_t)(n * 400) * 1024 + (c - 512);
        #pragma unroll
        for (int d = 0; d < 8; ++d) {
            const size_t o = (size_t)d * 1024;
            buf[d] = (xr[o] + xr[o + 512]) + (xr[o + PS] + xr[o + PS + 512]);
        }
        #pragma unroll 8
        for (int t = 0; t < 400; ++t) {
            const float xt = buf[t & 7];
            const int tn = t + 8;
            float nx = 0.f;
            if (tn < 400) {
                const size_t o = (size_t)tn * 1024;
                nx = (xr[o] + xr[o + 512]) + (xr[o + PS] + xr[o + PS + 512]);
            }
            buf[t & 7] = nx;
            const float sp = loihi_step(xt, u, v);
            if (t < 399) srow[(size_t)(t + 1) * 1024] = (sp != 0.f) ? (u16)0x3F80 : (u16)0;
        }
    }
}

// scan_c: combi (2 partials, stacked pairs at +256) -> out [n][c][t]
__global__ __launch_bounds__(64) void scan_c(const float* __restrict__ Xc,
                                             float* __restrict__ out)
{
    const int gid = blockIdx.x * 64 + threadIdx.x;   // 32*256 threads
    const int n = gid >> 8;
    const int c = gid & 255;
    const size_t PS = (size_t)12800 * 512;
    const float* xr = Xc + (size_t)(n * 400) * 512 + c;
    float* orow = out + ((size_t)n * 256 + c) * 400;
    orow[0] = 0.f;

    float buf[8];
    #pragma unroll
    for (int d = 0; d < 8; ++d) {
        const size_t o = (size_t)d * 512;
        buf[d] = (xr[o] + xr[o + 256]) + (xr[o + PS] + xr[o + PS + 256]);
    }
    float u = 0.f, v = 0.f;
    #pragma unroll 8
    for (int t = 0; t < 400; ++t) {
        const float xt = buf[t & 7];
        const int tn = t + 8;
        float nx = 0.f;
        if (tn < 400) {
            const size_t o = (size_t)tn * 512;
            nx = (xr[o] + xr[o + 256]) + (xr[o + PS] + xr[o + PS + 256]);
        }
        buf[t & 7] = nx;
        const float sp = loihi_step(xt, u, v);
        if (t < 399) orow[t + 1] = sp;
    }
}

extern "C" void kernel_launch(void* const* d_in, const int* in_sizes, int n_in,
                              void* d_out, int out_size, void* d_ws, size_t ws_size,
                              hipStream_t stream)
{
    const float* tact   = (const float*)d_in[0];  // [32][156][400]
    const float* vis    = (const float*)d_in[1];  // [32][6300][400]
    const float* W_tact = (const float*)d_in[2];  // [512][156]
    const float* W_vis  = (const float*)d_in[3];  // [512][6300]
    const float* W_comb = (const float*)d_in[4];  // [256][1024]
    float* out = (float*)d_out;                   // [32][256][400]

    const int NT = 32 * 400;            // 12800
    const int Ktp = 160;                // tact K pad (5 K-tiles)
    const int Kvp = 6304;               // vis K pad (197 K-tiles)
    const int Kc  = 1024;               // combi K (32 K-tiles)

    // ---- workspace carve-up: identical to rounds 5-7 ----
    char* p = (char*)d_ws;
    u16* Sv  = (u16*)p;                p += (size_t)NT * Kvp * 2;        // 161.4MB
    u16* St  = (u16*)p;                p += (size_t)NT * Ktp * 2;        //   4.1MB
    u16* Wt2 = (u16*)p;                p += (size_t)1024 * Ktp * 2;
    u16* Wv2 = (u16*)p;                p += (size_t)1024 * Kvp * 2;      //  12.9MB
    u16* Wc2 = (u16*)p;                p += (size_t)512 * Kc * 2;
    float* Xv = (float*)p;             p += (size_t)2 * NT * 1024 * 4;   // 104.9MB
    // aliases into Sv region (Sv dead after vis gemm; tact gemm runs after):
    float* Xt = (float*)Sv;                                        // [NT][1024] f32
    u16*   Sc = (u16*)((char*)Sv + (size_t)NT * 1024 * 4);         // [NT][1024] bf16
    float* Xc = (float*)((char*)Sv + (size_t)NT * 1024 * 4 + (size_t)NT * 1024 * 2); // [2][NT][512]

    // 1) weight splits (stacked 2 RNE planes)
    split_w2s<<<dim3((Kvp + 255) / 256, 512), 256, 0, stream>>>(W_vis,  Wv2, 512, 6300, Kvp);
    split_w2s<<<dim3((Ktp + 255) / 256, 512), 256, 0, stream>>>(W_tact, Wt2, 512, 156,  Ktp);
    split_w2s<<<dim3((Kc  + 255) / 256, 256), 256, 0, stream>>>(W_comb, Wc2, 256, 1024, Kc);

    // 2) spike transpose+convert
    cvt_sp<<<dim3(7, (Kvp + 63) / 64, 32), 256, 0, stream>>>(vis,  Sv, 6300, Kvp);
    cvt_sp<<<dim3(7, (Ktp + 63) / 64, 32), 256, 0, stream>>>(tact, St, 156,  Ktp);

    // 3) vis GEMM first (reads Sv), THEN tact GEMM (writes Xt over dead Sv)
    gemm8<<<dim3(1024 / 256, NT / 256, 2), 512, 0, stream>>>(Wv2, Sv, Xv, 1024, Kvp, 99, 197);
    gemm8<<<dim3(1024 / 256, NT / 256, 1), 512, 0, stream>>>(Wt2, St, Xt, 1024, Ktp, 5, 5);

    // 4) scan layers 1+2 -> combi spikes (bf16, [nt][1024])
    scan_ab<<<dim3((32 * 1024) / 64), 64, 0, stream>>>(Xt, Xv, Sc);

    // 5) combi GEMM (z=2 K-chunks of 16 tiles) + scan -> out
    gemm8<<<dim3(512 / 256, NT / 256, 2), 512, 0, stream>>>(Wc2, Sc, Xc, 512, Kc, 16, 32);
    scan_c<<<dim3((32 * 256) / 64), 64, 0, stream>>>(Xc, out);

    (void)in_sizes; (void)n_in; (void)out_size; (void)ws_size;
}

// Round 9
// 679.396 us; speedup vs baseline: 3.2638x; 3.2638x over previous
//
#include <hip/hip_runtime.h>

// Loihi SNN, 3 layers of (GEMM -> Loihi scan -> delay).
// Round 9: round-7 base (3-deep ring, 96KB, vmcnt(4), (512,2) bounds —
// round 8's (512,4) forced a 64-VGPR cap and spilled the 128-VGPR acc)
// with ONE barrier per K-tile (hazard-proven: all prior-window ds_reads are
// consumed before any wave passes the boundary barrier; window-i stages
// target slot (i+2)%3 which no wave still reads; vmcnt retires FIFO so
// vmcnt(4) guarantees the current tile's 4 loads landed). Waves slip ->
// ds_read/MFMA overlap across waves. Scans restored to depth-16 pipelines.
//
// W-planes stacked along M (single A stream): W2 = [W_hi; W_mid], M2=2C.
// Scans sum plane pairs (X[c] + X[c+C]) and K-split partials in fixed order.

typedef unsigned short u16;
typedef unsigned int u32;
typedef __attribute__((ext_vector_type(8))) short short8;
typedef __attribute__((ext_vector_type(4))) float f32x4;

#define GLOAD16(g, l)                                                         \
    __builtin_amdgcn_global_load_lds(                                         \
        (const __attribute__((address_space(1))) u32*)(g),                    \
        (__attribute__((address_space(3))) u32*)(l), 16, 0, 0)

__device__ __forceinline__ u16 f2bf_trunc(float x) {
    return (u16)(__float_as_uint(x) >> 16);
}

// ---------------- W -> stacked 2-plane RNE split ----------------
__global__ void split_w2s(const float* __restrict__ W, u16* __restrict__ W2,
                          int C, int K, int KLD)
{
    const int c = blockIdx.y;
    const int k = blockIdx.x * 256 + threadIdx.x;
    if (k >= KLD) return;
    float w = (k < K) ? W[(size_t)c * K + k] : 0.f;
    u32 b  = __float_as_uint(w);
    u32 hb = (b + 0x7FFFu + ((b >> 16) & 1u)) & 0xFFFF0000u;
    float r = w - __uint_as_float(hb);
    u32 rb = __float_as_uint(r);
    u32 mb = (rb + 0x7FFFu + ((rb >> 16) & 1u)) & 0xFFFF0000u;
    W2[(size_t)c * KLD + k]       = (u16)(hb >> 16);
    W2[((size_t)C + c) * KLD + k] = (u16)(mb >> 16);
}

// ------- spikes fp32 [n][I][400] -> bf16 [n*400+t][KLD] (transpose) -------
__global__ __launch_bounds__(256) void cvt_sp(const float* __restrict__ S,
                                              u16* __restrict__ Sp,
                                              int I, int KLD)
{
    __shared__ u16 tile[64][80];
    const int n  = blockIdx.z;
    const int i0 = blockIdx.y * 64;
    const int t0 = blockIdx.x * 64;
    const int tid = threadIdx.x;

    const int il = tid >> 2;
    const int q  = tid & 3;
    const int gi = i0 + il;
    const bool iok = gi < I;
    const float* srow = S + ((size_t)n * I + gi) * 400 + t0;

    #pragma unroll
    for (int s = 0; s < 4; ++s) {
        const int fi = s * 4 + q;
        const int tl = fi * 4;
        float4 v = make_float4(0.f, 0.f, 0.f, 0.f);
        if (iok && (t0 + tl) < 400)
            v = *(const float4*)(srow + tl);
        tile[tl + 0][il] = f2bf_trunc(v.x);
        tile[tl + 1][il] = f2bf_trunc(v.y);
        tile[tl + 2][il] = f2bf_trunc(v.z);
        tile[tl + 3][il] = f2bf_trunc(v.w);
    }
    __syncthreads();

    const int tl = tid >> 2;
    const int iq = tid & 3;
    const int t  = t0 + tl;
    const int go = i0 + iq * 16;
    if (t < 400 && go < KLD) {
        u16* dst = Sp + (size_t)(n * 400 + t) * KLD + go;
        *(short8*)(dst)     = *(const short8*)&tile[tl][iq * 16];
        *(short8*)(dst + 8) = *(const short8*)&tile[tl][iq * 16 + 8];
    }
}

// ---------------- overlap-pipelined bf16 MFMA GEMM ----------------
// X[z][nt][c] = sum_{k in chunk z} A[c][k] * B[nt][k]
// 256(M) x 256(N) tile, BK=32, 8 waves (2M x 4N), wave = 128x64 output.
// LDS: A ring 3x8192 u16 @0 ; B ring 3x8192 u16 @24576  (96 KB total)
__global__ __launch_bounds__(512, 2) void gemm8(
    const u16* __restrict__ A,   // [M2][KLD]
    const u16* __restrict__ B,   // [12800][KLD]
    float* __restrict__ Xbase,   // [z][12800][M2]
    int M2, int KLD, int ktPerZ, int ktTotal)
{
    __shared__ u16 lds[49152];   // 96 KB

    // bijective XCD-aware block swizzle (all launches have nwg % 8 == 0)
    const int Dx = gridDim.x, Dy = gridDim.y;
    int f = blockIdx.x + Dx * (blockIdx.y + Dy * blockIdx.z);
    const int nwg = Dx * Dy * gridDim.z;
    f = (f & 7) * (nwg >> 3) + (f >> 3);
    const int bx = f % Dx;
    const int by = (f / Dx) % Dy;
    const int bz = f / (Dx * Dy);

    const int c0  = bx * 256;
    const int nt0 = by * 256;
    const int kt0 = bz * ktPerZ;
    const int nk  = min(ktTotal - kt0, ktPerZ);
    float* __restrict__ X = Xbase + (size_t)bz * 12800 * M2;

    const int tid  = threadIdx.x;
    const int lane = tid & 63, w = tid >> 6;

    // staging: LDS granule (row=tid>>2, gc=tid&3) <- global granule-col
    // inverse-swizzled with key (row>>1)&3  [both-sides-or-neither, rule 21]
    const int sr  = tid >> 2;                       // 0..127 (half j adds 128)
    const int sgc = (tid & 3) ^ ((sr >> 1) & 3);
    const u16* gA0 = A + (size_t)(c0 + sr) * KLD + (size_t)kt0 * 32 + sgc * 8;
    const u16* gA1 = gA0 + (size_t)128 * KLD;
    const u16* gB0 = B + (size_t)(nt0 + sr) * KLD + (size_t)kt0 * 32 + sgc * 8;
    const u16* gB1 = gB0 + (size_t)128 * KLD;
    u16* const lA0 = &lds[0     + w * 512];
    u16* const lA1 = &lds[4096  + w * 512];
    u16* const lB0 = &lds[24576 + w * 512];
    u16* const lB1 = &lds[24576 + 4096 + w * 512];

#define STAGE_A(i, b) { GLOAD16(gA0 + (size_t)(i) * 32, lA0 + (b) * 8192);    \
                        GLOAD16(gA1 + (size_t)(i) * 32, lA1 + (b) * 8192); }
#define STAGE_B(i, b) { GLOAD16(gB0 + (size_t)(i) * 32, lB0 + (b) * 8192);    \
                        GLOAD16(gB1 + (size_t)(i) * 32, lB1 + (b) * 8192); }
#define FENCE() asm volatile("" ::: "memory")

    // fragment reads: granule col = l16 ^ ((row>>1)&3); row ≡ l15 (mod 16)
    const int wm = w >> 2, wn = w & 3;
    const int l15 = lane & 15, l16 = lane >> 4;
    const int swz  = (l16 ^ ((l15 >> 1) & 3)) * 8;
    const int aOff = (wm * 128 + l15) * 32 + swz;        // + mf*512 + buf*8192
    const int bOff = 24576 + (wn * 64 + l15) * 32 + swz; // + nf*512 + buf*8192

    f32x4 acc[8][4];
    #pragma unroll
    for (int i = 0; i < 8; ++i)
        #pragma unroll
        for (int j = 0; j < 4; ++j)
            acc[i][j] = (f32x4){0.f, 0.f, 0.f, 0.f};

    // prologue: stage tiles 0 and 1
    STAGE_A(0, 0); STAGE_B(0, 0);
    if (nk > 1) { STAGE_A(1, 1); STAGE_B(1, 1); }

    for (int i = 0; i < nk; ++i) {
        const int bb = (i % 3) * 8192;
        const int bs = (i + 2) % 3;

        // K-tile boundary: counted vmcnt (FIFO -> oldest tile landed), then
        // the single collective barrier of this K-tile.
        if (i < nk - 1) { asm volatile("s_waitcnt vmcnt(4)" ::: "memory"); }
        else            { asm volatile("s_waitcnt vmcnt(0)" ::: "memory"); }
        __builtin_amdgcn_s_barrier();
        FENCE();

        // issue next+1 tile's A stage first (max in-flight time)
        if (i + 2 < nk) STAGE_A(i + 2, bs);
        FENCE();

        // phase 1: A m-frags 0..3 + B n-frags 0..3 -> 16 MFMA
        short8 a1[4], bf[4];
        #pragma unroll
        for (int mf = 0; mf < 4; ++mf)
            a1[mf] = *(const short8*)&lds[bb + aOff + mf * 512];
        #pragma unroll
        for (int nf = 0; nf < 4; ++nf)
            bf[nf] = *(const short8*)&lds[bb + bOff + nf * 512];
        __builtin_amdgcn_s_setprio(1);
        #pragma unroll
        for (int mf = 0; mf < 4; ++mf)
            #pragma unroll
            for (int nf = 0; nf < 4; ++nf)
                acc[mf][nf] = __builtin_amdgcn_mfma_f32_16x16x32_bf16(
                    a1[mf], bf[nf], acc[mf][nf], 0, 0, 0);
        __builtin_amdgcn_s_setprio(0);
        FENCE();

        // issue next+1 tile's B stage, then phase 2 (B reused in regs)
        if (i + 2 < nk) STAGE_B(i + 2, bs);
        FENCE();
        short8 a2[4];
        #pragma unroll
        for (int mf = 0; mf < 4; ++mf)
            a2[mf] = *(const short8*)&lds[bb + aOff + (mf + 4) * 512];
        __builtin_amdgcn_s_setprio(1);
        #pragma unroll
        for (int mf = 0; mf < 4; ++mf)
            #pragma unroll
            for (int nf = 0; nf < 4; ++nf)
                acc[mf + 4][nf] = __builtin_amdgcn_mfma_f32_16x16x32_bf16(
                    a2[mf], bf[nf], acc[mf + 4][nf], 0, 0, 0);
        __builtin_amdgcn_s_setprio(0);
        FENCE();
    }

    // epilogue: D col=lane&15 -> nt, row=(lane>>4)*4+reg -> c (m89-verified)
    #pragma unroll
    for (int mf = 0; mf < 8; ++mf) {
        const int c = c0 + wm * 128 + mf * 16 + l16 * 4;
        #pragma unroll
        for (int nf = 0; nf < 4; ++nf) {
            const int nt = nt0 + wn * 64 + nf * 16 + l15;
            *(f32x4*)&X[(size_t)nt * M2 + c] = acc[mf][nf];
        }
    }
#undef STAGE_A
#undef STAGE_B
#undef FENCE
}

// ---------------- Loihi scans (16-deep pipelined loads, 64-thr blocks) -----
__device__ __forceinline__ float loihi_step(float xt, float& u, float& v)
{
    u = truncf(u * 0.75f) + 64.f * xt;
    v = truncf(v * 0.96875f) + u;
    if (v >= 5120.f) { v = 0.f; return 1.f; }
    return 0.f;
}

// scan_ab: tact (stacked pair) + vis (2 partials, stacked pairs) -> Sc bf16
__global__ __launch_bounds__(64) void scan_ab(const float* __restrict__ Xt,
                                              const float* __restrict__ Xv,
                                              u16* __restrict__ Sc)
{
    const int gid = blockIdx.x * 64 + threadIdx.x;   // 32*1024 threads
    const int n = gid >> 10;
    const int c = gid & 1023;
    const size_t PS = (size_t)12800 * 1024;          // vis partial stride

    u16* srow = Sc + (size_t)(n * 400) * 1024 + c;
    srow[0] = 0;

    float buf[16];
    float u = 0.f, v = 0.f;

    if (c < 512) {
        const float* xr = Xt + (size_t)(n * 400) * 1024 + c;
        #pragma unroll
        for (int d = 0; d < 16; ++d) {
            const size_t o = (size_t)d * 1024;
            buf[d] = xr[o] + xr[o + 512];
        }
        #pragma unroll 16
        for (int t = 0; t < 400; ++t) {
            const float xt = buf[t & 15];
            const int tn = t + 16;
            float nx = 0.f;
            if (tn < 400) {
                const size_t o = (size_t)tn * 1024;
                nx = xr[o] + xr[o + 512];
            }
            buf[t & 15] = nx;
            const float sp = loihi_step(xt, u, v);
            if (t < 399) srow[(size_t)(t + 1) * 1024] = (sp != 0.f) ? (u16)0x3F80 : (u16)0;
        }
    } else {
        const float* xr = Xv + (size_t)(n * 400) * 1024 + (c - 512);
        #pragma unroll
        for (int d = 0; d < 16; ++d) {
            const size_t o = (size_t)d * 1024;
            buf[d] = (xr[o] + xr[o + 512]) + (xr[o + PS] + xr[o + PS + 512]);
        }
        #pragma unroll 16
        for (int t = 0; t < 400; ++t) {
            const float xt = buf[t & 15];
            const int tn = t + 16;
            float nx = 0.f;
            if (tn < 400) {
                const size_t o = (size_t)tn * 1024;
                nx = (xr[o] + xr[o + 512]) + (xr[o + PS] + xr[o + PS + 512]);
            }
            buf[t & 15] = nx;
            const float sp = loihi_step(xt, u, v);
            if (t < 399) srow[(size_t)(t + 1) * 1024] = (sp != 0.f) ? (u16)0x3F80 : (u16)0;
        }
    }
}

// scan_c: combi (2 partials, stacked pairs at +256) -> out [n][c][t]
__global__ __launch_bounds__(64) void scan_c(const float* __restrict__ Xc,
                                             float* __restrict__ out)
{
    const int gid = blockIdx.x * 64 + threadIdx.x;   // 32*256 threads
    const int n = gid >> 8;
    const int c = gid & 255;
    const size_t PS = (size_t)12800 * 512;
    const float* xr = Xc + (size_t)(n * 400) * 512 + c;
    float* orow = out + ((size_t)n * 256 + c) * 400;
    orow[0] = 0.f;

    float buf[16];
    #pragma unroll
    for (int d = 0; d < 16; ++d) {
        const size_t o = (size_t)d * 512;
        buf[d] = (xr[o] + xr[o + 256]) + (xr[o + PS] + xr[o + PS + 256]);
    }
    float u = 0.f, v = 0.f;
    #pragma unroll 16
    for (int t = 0; t < 400; ++t) {
        const float xt = buf[t & 15];
        const int tn = t + 16;
        float nx = 0.f;
        if (tn < 400) {
            const size_t o = (size_t)tn * 512;
            nx = (xr[o] + xr[o + 256]) + (xr[o + PS] + xr[o + PS + 256]);
        }
        buf[t & 15] = nx;
        const float sp = loihi_step(xt, u, v);
        if (t < 399) orow[t + 1] = sp;
    }
}

extern "C" void kernel_launch(void* const* d_in, const int* in_sizes, int n_in,
                              void* d_out, int out_size, void* d_ws, size_t ws_size,
                              hipStream_t stream)
{
    const float* tact   = (const float*)d_in[0];  // [32][156][400]
    const float* vis    = (const float*)d_in[1];  // [32][6300][400]
    const float* W_tact = (const float*)d_in[2];  // [512][156]
    const float* W_vis  = (const float*)d_in[3];  // [512][6300]
    const float* W_comb = (const float*)d_in[4];  // [256][1024]
    float* out = (float*)d_out;                   // [32][256][400]

    const int NT = 32 * 400;            // 12800
    const int Ktp = 160;                // tact K pad (5 K-tiles)
    const int Kvp = 6304;               // vis K pad (197 K-tiles)
    const int Kc  = 1024;               // combi K (32 K-tiles)

    // ---- workspace carve-up: identical to rounds 5-8 ----
    char* p = (char*)d_ws;
    u16* Sv  = (u16*)p;                p += (size_t)NT * Kvp * 2;        // 161.4MB
    u16* St  = (u16*)p;                p += (size_t)NT * Ktp * 2;        //   4.1MB
    u16* Wt2 = (u16*)p;                p += (size_t)1024 * Ktp * 2;
    u16* Wv2 = (u16*)p;                p += (size_t)1024 * Kvp * 2;      //  12.9MB
    u16* Wc2 = (u16*)p;                p += (size_t)512 * Kc * 2;
    float* Xv = (float*)p;             p += (size_t)2 * NT * 1024 * 4;   // 104.9MB
    // aliases into Sv region (Sv dead after vis gemm; tact gemm runs after):
    float* Xt = (float*)Sv;                                        // [NT][1024] f32
    u16*   Sc = (u16*)((char*)Sv + (size_t)NT * 1024 * 4);         // [NT][1024] bf16
    float* Xc = (float*)((char*)Sv + (size_t)NT * 1024 * 4 + (size_t)NT * 1024 * 2); // [2][NT][512]

    // 1) weight splits (stacked 2 RNE planes)
    split_w2s<<<dim3((Kvp + 255) / 256, 512), 256, 0, stream>>>(W_vis,  Wv2, 512, 6300, Kvp);
    split_w2s<<<dim3((Ktp + 255) / 256, 512), 256, 0, stream>>>(W_tact, Wt2, 512, 156,  Ktp);
    split_w2s<<<dim3((Kc  + 255) / 256, 256), 256, 0, stream>>>(W_comb, Wc2, 256, 1024, Kc);

    // 2) spike transpose+convert
    cvt_sp<<<dim3(7, (Kvp + 63) / 64, 32), 256, 0, stream>>>(vis,  Sv, 6300, Kvp);
    cvt_sp<<<dim3(7, (Ktp + 63) / 64, 32), 256, 0, stream>>>(tact, St, 156,  Ktp);

    // 3) vis GEMM first (reads Sv), THEN tact GEMM (writes Xt over dead Sv)
    gemm8<<<dim3(1024 / 256, NT / 256, 2), 512, 0, stream>>>(Wv2, Sv, Xv, 1024, Kvp, 99, 197);
    gemm8<<<dim3(1024 / 256, NT / 256, 1), 512, 0, stream>>>(Wt2, St, Xt, 1024, Ktp, 5, 5);

    // 4) scan layers 1+2 -> combi spikes (bf16, [nt][1024])
    scan_ab<<<dim3((32 * 1024) / 64), 64, 0, stream>>>(Xt, Xv, Sc);

    // 5) combi GEMM (z=2 K-chunks of 16 tiles) + scan -> out
    gemm8<<<dim3(512 / 256, NT / 256, 2), 512, 0, stream>>>(Wc2, Sc, Xc, 512, Kc, 16, 32);
    scan_c<<<dim3((32 * 256) / 64), 64, 0, stream>>>(Xc, out);

    (void)in_sizes; (void)n_in; (void)out_size; (void)ws_size;
}